// Round 8
// baseline (13482.207 us; speedup 1.0000x reference)
//
#include <hip/hip_runtime.h>
#include <hip/hip_bf16.h>

#define TT 2048
#define HH 1024
#define GH 4096

__device__ __forceinline__ float sigm(float x){ return 1.0f / (1.0f + __expf(-x)); }

// -------- Phase 1: plain fp32 tiled GEMM (validated r3-r7) --------
// gx[t][j] = sum_k emb[tok[t]][k] * Wih[j][k] + bih[j] + bhh[j]
#define BM 128
#define BN 64
#define BK 32

__global__ __launch_bounds__(256) void gemm_simple(
    const int* __restrict__ tokens,
    const float* __restrict__ emb,
    const float* __restrict__ Wih,
    const float* __restrict__ bih,
    const float* __restrict__ bhh,
    float* __restrict__ gx)
{
  __shared__ float As[BM][BK+1];
  __shared__ float Bs[BN][BK+1];
  __shared__ int tok_s[BM];

  const int tid = threadIdx.x;
  const int bn = blockIdx.x;      // 0..63
  const int bm = blockIdx.y;      // 0..15
  const int m0 = bm*BM, n0 = bn*BN;

  if (tid < BM) tok_s[tid] = tokens[m0 + tid];
  __syncthreads();

  const int tm = tid >> 4;
  const int tn = tid & 15;

  float acc[8][4];
  #pragma unroll
  for (int i = 0; i < 8; ++i)
    #pragma unroll
    for (int j = 0; j < 4; ++j) acc[i][j] = 0.0f;

  for (int k0 = 0; k0 < HH; k0 += BK) {
    for (int idx = tid; idx < BM*BK; idx += 256) {
      int r = idx >> 5, c = idx & 31;
      As[r][c] = emb[(size_t)tok_s[r]*HH + k0 + c];
    }
    for (int idx = tid; idx < BN*BK; idx += 256) {
      int r = idx >> 5, c = idx & 31;
      Bs[r][c] = Wih[(size_t)(n0 + r)*HH + k0 + c];
    }
    __syncthreads();
    #pragma unroll
    for (int k = 0; k < BK; ++k) {
      float a[8], b[4];
      #pragma unroll
      for (int i = 0; i < 8; ++i) a[i] = As[tm*8 + i][k];
      #pragma unroll
      for (int j = 0; j < 4; ++j) b[j] = Bs[tn*4 + j][k];
      #pragma unroll
      for (int i = 0; i < 8; ++i)
        #pragma unroll
        for (int j = 0; j < 4; ++j)
          acc[i][j] = fmaf(a[i], b[j], acc[i][j]);
    }
    __syncthreads();
  }

  float bias[4];
  #pragma unroll
  for (int j = 0; j < 4; ++j) {
    int col = n0 + tn*4 + j;
    bias[j] = bih[col] + bhh[col];
  }
  #pragma unroll
  for (int i = 0; i < 8; ++i) {
    int r = m0 + tm*8 + i;
    #pragma unroll
    for (int j = 0; j < 4; ++j)
      gx[(size_t)r*GH + (n0 + tn*4 + j)] = acc[i][j] + bias[j];
  }
}

// -------- Phase 2: barrier-free wave-autonomous persistent scan --------
// 64 blocks x 8 waves; wave w owns outputs o0=b*16+2w, o1=o0+1.
// Each wave polls ALL 1024 slots (coalesced lane+64j), dots in registers,
// folded shuffle-reduce, act+publish in lanes 0/32. No LDS, no barriers.
// Safety: every wave publishes AND reads every slot each step => publisher
// reaches tag t+2 only after all waves consumed tag t => 2-parity is race-free.
#define GBLK 64
#define NTH 512

__global__ __launch_bounds__(NTH, 2) void lstm_scan(
    const float* __restrict__ gx,
    const float* __restrict__ Whh,
    unsigned long long* slots,     // [2][1024] {tag<<32 | fp32 h}
    float* __restrict__ out)       // [2048] fp32 = h ; c
{
  const int b   = blockIdx.x;
  const int tid = threadIdx.x;
  const int lane = tid & 63;
  const int wv   = tid >> 6;          // 0..7
  const int o0 = (b << 4) + (wv << 1);
  const int o1 = o0 + 1;

  // w[r][j] = Whh[(r&3)*1024 + (r>=4 ? o1 : o0)][lane + 64*j]
  // r = out_sel*4 + gate; reduce leaves S_r at lanes with (lane&7)==r.
  float w[8][16];
  #pragma unroll
  for (int r = 0; r < 8; ++r) {
    const int jrow = ((r & 3) << 10) + ((r >> 2) ? o1 : o0);
    const float* wr = Whh + (size_t)jrow * HH + lane;
    #pragma unroll
    for (int j = 0; j < 16; ++j)
      w[r][j] = wr[64 * j];
  }

  const bool actlane = (lane == 0) || (lane == 32);
  const int myout = (lane == 0) ? o0 : o1;
  float cst = 0.0f;
  float g4[4] = {0.f, 0.f, 0.f, 0.f};
  if (actlane) {
    #pragma unroll
    for (int g = 0; g < 4; ++g) g4[g] = gx[(g << 10) + myout];   // t = 0
  }

  float h[16];
  #pragma unroll
  for (int j = 0; j < 16; ++j) h[j] = 0.0f;    // h(0) = 0

  for (int t = 0; t < TT; ++t) {
    if (t > 0) {
      const unsigned long long* sb = slots + (size_t)(t & 1) * 1024;
      const unsigned tg = (unsigned)t;
      unsigned long long v[16];
      #pragma unroll
      for (int j = 0; j < 16; ++j)            // issue all 16 in parallel
        v[j] = __hip_atomic_load(&sb[lane + 64*j], __ATOMIC_RELAXED, __HIP_MEMORY_SCOPE_AGENT);
      #pragma unroll
      for (int j = 0; j < 16; ++j)            // fix stragglers
        while ((unsigned)(v[j] >> 32) != tg)
          v[j] = __hip_atomic_load(&sb[lane + 64*j], __ATOMIC_RELAXED, __HIP_MEMORY_SCOPE_AGENT);
      #pragma unroll
      for (int j = 0; j < 16; ++j) h[j] = __uint_as_float((unsigned)v[j]);
    }

    float acc[8];
    #pragma unroll
    for (int r = 0; r < 8; ++r) acc[r] = 0.0f;
    #pragma unroll
    for (int j = 0; j < 16; ++j) {
      const float hj = h[j];
      #pragma unroll
      for (int r = 0; r < 8; ++r) acc[r] = fmaf(w[r][j], hj, acc[r]);
    }

    // folded butterfly reduce: 7 fold-shfl + 3 plain -> lane l holds S_{l&7}
    float v4[4];
    #pragma unroll
    for (int i = 0; i < 4; ++i) {
      float lo = acc[2*i], hi = acc[2*i+1];
      float a = (lane & 1) ? hi : lo;
      float q = (lane & 1) ? lo : hi;
      v4[i] = a + __shfl_xor(q, 1);
    }
    float v2[2];
    #pragma unroll
    for (int i = 0; i < 2; ++i) {
      float lo = v2[0], hi = v2[0];   // placeholder to avoid warnings; overwritten below
      lo = v4[2*i]; hi = v4[2*i+1];
      float a = (lane & 2) ? hi : lo;
      float q = (lane & 2) ? lo : hi;
      v2[i] = a + __shfl_xor(q, 2);
    }
    float v1;
    {
      float lo = v2[0], hi = v2[1];
      float a = (lane & 4) ? hi : lo;
      float q = (lane & 4) ? lo : hi;
      v1 = a + __shfl_xor(q, 4);
    }
    v1 += __shfl_xor(v1, 8);
    v1 += __shfl_xor(v1, 16);
    v1 += __shfl_xor(v1, 32);

    // gather this lane-half's 4 gate sums
    const int base = (lane >= 32) ? 4 : 0;
    float xi = __shfl(v1, base + 0);
    float xf = __shfl(v1, base + 1);
    float xg = __shfl(v1, base + 2);
    float xo = __shfl(v1, base + 3);

    if (actlane) {
      xi += g4[0]; xf += g4[1]; xg += g4[2]; xo += g4[3];
      cst = sigm(xf)*cst + sigm(xi)*tanhf(xg);
      float hnew = sigm(xo)*tanhf(cst);
      if (t == TT-1) {
        out[myout]        = hnew;
        out[1024 + myout] = cst;
      } else {
        unsigned long long* db = slots + (size_t)((t+1) & 1) * 1024;
        unsigned long long pv =
            (((unsigned long long)(unsigned)(t+1)) << 32) |
            (unsigned long long)__float_as_uint(hnew);
        __hip_atomic_store(&db[myout], pv, __ATOMIC_RELAXED, __HIP_MEMORY_SCOPE_AGENT);
        #pragma unroll
        for (int g = 0; g < 4; ++g)           // prefetch next step's gx
          g4[g] = gx[(size_t)(t+1)*GH + (g << 10) + myout];
      }
    }
  }
}

// fallback: ws too small -> zeros
__global__ void zero_out(float* out){
  int i = blockIdx.x*256 + threadIdx.x;
  if (i < 2048) out[i] = 0.0f;
}

extern "C" void kernel_launch(void* const* d_in, const int* in_sizes, int n_in,
                              void* d_out, int out_size, void* d_ws, size_t ws_size,
                              hipStream_t stream) {
  (void)in_sizes; (void)n_in; (void)out_size;
  const int* tokens = (const int*)d_in[0];
  const float* emb  = (const float*)d_in[1];
  const float* Wih  = (const float*)d_in[2];
  const float* Whh  = (const float*)d_in[3];
  const float* bih  = (const float*)d_in[4];
  const float* bhh  = (const float*)d_in[5];
  float* out = (float*)d_out;

  // ws: [0,16K) slots[2][1024] u64 | [16K, ...) gx fp32 [2048][4096]
  unsigned long long* slots = (unsigned long long*)d_ws;
  float* gx = (float*)((char*)d_ws + 16384);
  const size_t needF32 = 16384 + (size_t)TT*GH*sizeof(float);

  hipMemsetAsync(slots, 0, 16384, stream);
  if (ws_size >= needF32) {
    gemm_simple<<<dim3(64,16), dim3(256), 0, stream>>>(tokens, emb, Wih, bih, bhh, gx);
    lstm_scan<<<dim3(GBLK), dim3(NTH), 0, stream>>>(gx, Whh, slots, out);
  } else {
    zero_out<<<dim3(8), dim3(256), 0, stream>>>(out);
  }
}